// Round 1
// baseline (499.179 us; speedup 1.0000x reference)
//
#include <hip/hip_runtime.h>

#define B_ 4
#define C_ 256
#define CQ_ 32
#define N_ 4096
#define LOG2E 1.44269504088896340736f

typedef __attribute__((ext_vector_type(8))) short bf16x8;
typedef __attribute__((ext_vector_type(4))) float f32x4;

static __device__ __forceinline__ unsigned short f2bf(float f) {
    unsigned u = __builtin_bit_cast(unsigned, f);
    u += 0x7fffu + ((u >> 16) & 1u);
    return (unsigned short)(u >> 16);
}

static __device__ __forceinline__ float fexp2(float x) {
#if __has_builtin(__builtin_amdgcn_exp2f)
    return __builtin_amdgcn_exp2f(x);
#else
    return exp2f(x);
#endif
}

// ---------- k0: weight transpose (+ fold log2(e) into Wq) ----------
// WqkT[c][o] : o<32 -> Wq[o][c]*LOG2E ; o>=32 -> Wk[o-32][c]
// WvT[cp][c] = Wv[c][cp]
__global__ void k0_wprep(const float* __restrict__ Wq, const float* __restrict__ Wk,
                         const float* __restrict__ Wv, float* __restrict__ WqkT,
                         float* __restrict__ WvT) {
    int t = blockIdx.x * 256 + threadIdx.x;
    if (t < 256 * 64) {
        int c = t >> 6, o = t & 63;
        WqkT[t] = (o < 32) ? Wq[o * C_ + c] * LOG2E : Wk[(o - 32) * C_ + c];
    }
    int t2 = t - 256 * 64;
    if (t2 >= 0 && t2 < 256 * 256) {
        int cp = t2 >> 8, c = t2 & 255;
        WvT[t2] = Wv[c * C_ + cp];
    }
}

// ---------- k1: q/k prep -> bf16 [B][N][32] (q scaled by LOG2E incl bias) ----------
__global__ __launch_bounds__(64) void k1_qk(const float* __restrict__ x,
        const float* __restrict__ WqkT, const float* __restrict__ bq,
        const float* __restrict__ bk, unsigned short* __restrict__ qb,
        unsigned short* __restrict__ ktb) {
    int b = blockIdx.z;
    int isk = blockIdx.y;
    int n = blockIdx.x * 64 + threadIdx.x;
    const float* xp = x + (size_t)b * C_ * N_ + n;
    float acc[32];
    const float* bias = isk ? bk : bq;
    float bs = isk ? 1.0f : LOG2E;
#pragma unroll
    for (int o = 0; o < 32; ++o) acc[o] = bias[o] * bs;
    const float* wbase = WqkT + (isk ? 32 : 0);
#pragma unroll 4
    for (int c = 0; c < C_; ++c) {
        float xv = xp[(size_t)c * N_];
        const float* wr = wbase + c * 64;  // uniform -> s_loads
#pragma unroll
        for (int o = 0; o < 32; ++o) acc[o] += wr[o] * xv;
    }
    unsigned short* dst = (isk ? ktb : qb) + ((size_t)b * N_ + n) * 32;
    unsigned pk[16];
#pragma unroll
    for (int i = 0; i < 16; ++i)
        pk[i] = (unsigned)f2bf(acc[2 * i]) | ((unsigned)f2bf(acc[2 * i + 1]) << 16);
#pragma unroll
    for (int i = 0; i < 4; ++i)
        ((uint4*)dst)[i] = make_uint4(pk[4 * i], pk[4 * i + 1], pk[4 * i + 2], pk[4 * i + 3]);
}

// ---------- k2: per-column (per-m) stats: M'[m]=max_n S', Wcol[m]=1/Z ----------
// S' tile via mfma(A=q rows n, B=kt cols m). D: col m = lane&15 (fixed/lane),
// rows n = (lane>>4)*4+r. Online max/sum per lane, xor-reduce over lane>>4.
__global__ __launch_bounds__(256) void k2_stats(const unsigned short* __restrict__ qb,
        const unsigned short* __restrict__ ktb, float* __restrict__ Mcol,
        float* __restrict__ Wcol) {
    int b = blockIdx.y;
    int lane = threadIdx.x & 63;
    int wv = threadIdx.x >> 6;
    int m0 = blockIdx.x * 64 + wv * 16;
    int r16 = lane & 15, g = lane >> 4;
    bf16x8 kf = *(const bf16x8*)(ktb + ((size_t)b * N_ + m0 + r16) * 32 + 8 * g);
    float mx = -INFINITY, sum = 0.0f;
    const unsigned short* qbase = qb + (size_t)b * N_ * 32 + r16 * 32 + 8 * g;
#pragma unroll 4
    for (int n0 = 0; n0 < N_; n0 += 16) {
        bf16x8 qf = *(const bf16x8*)(qbase + (size_t)n0 * 32);
        f32x4 d = __builtin_amdgcn_mfma_f32_16x16x32_bf16(qf, kf, (f32x4){0, 0, 0, 0}, 0, 0, 0);
        float tm = fmaxf(fmaxf(d[0], d[1]), fmaxf(d[2], d[3]));
        float nm = fmaxf(mx, tm);
        sum = sum * fexp2(mx - nm) + fexp2(d[0] - nm) + fexp2(d[1] - nm) +
              fexp2(d[2] - nm) + fexp2(d[3] - nm);
        mx = nm;
    }
#pragma unroll
    for (int dlt = 16; dlt < 64; dlt <<= 1) {
        float omx = __shfl_xor(mx, dlt);
        float osum = __shfl_xor(sum, dlt);
        float nm = fmaxf(mx, omx);
        sum = sum * fexp2(mx - nm) + osum * fexp2(omx - nm);
        mx = nm;
    }
    if (lane < 16) {
        Mcol[(size_t)b * N_ + m0 + lane] = mx;
        Wcol[(size_t)b * N_ + m0 + lane] = 1.0f / sum;
    }
}

// ---------- k3: v prep, pre-scaled by 1/Z: vtb[B][C][N] bf16 ----------
__global__ __launch_bounds__(256) void k3_v(const float* __restrict__ x,
        const float* __restrict__ WvT, const float* __restrict__ bv,
        const float* __restrict__ Wcol, unsigned short* __restrict__ vtb) {
    int b = blockIdx.z;
    int c0 = blockIdx.y * 32;
    int m = blockIdx.x * 256 + threadIdx.x;
    const float* xp = x + (size_t)b * C_ * N_ + m;
    float acc[32];
#pragma unroll
    for (int j = 0; j < 32; ++j) acc[j] = bv[c0 + j];
#pragma unroll 4
    for (int cp = 0; cp < C_; ++cp) {
        float xv = xp[(size_t)cp * N_];
        const float* wr = WvT + cp * C_ + c0;  // contiguous, uniform -> s_loads
#pragma unroll
        for (int j = 0; j < 32; ++j) acc[j] += wr[j] * xv;
    }
    float wm = Wcol[(size_t)b * N_ + m];
#pragma unroll
    for (int j = 0; j < 32; ++j)
        vtb[((size_t)b * C_ + c0 + j) * N_ + m] = f2bf(acc[j] * wm);
}

// ---------- k4: PV with recomputed S^T, exp2, LDS transpose, fused epilogue ----------
// 8 waves: wave w -> rows n_base = bx*64 + (w&3)*16, cols c_base = (w>>2)*128.
// Per 32-m step: S^T tiles (mfma(kt,q)) -> D rows = m (4/lane), col n = lane&15
//  -> exp2(S'-M') -> pack 4 bf16 -> 2x ds_write_b64 into [n=16][m=32] tile,
//     8B-blocks XOR-swizzled by (row&6) for bank-floor;
//  -> ds_read_b128 A-frag; 8x mfma with vt B-frags (prefetched).
__global__ __launch_bounds__(512, 2) void k4_pv(const float* __restrict__ x,
        const unsigned short* __restrict__ qb, const unsigned short* __restrict__ ktb,
        const unsigned short* __restrict__ vtb, const float* __restrict__ Mcol,
        const float* __restrict__ gamma, float* __restrict__ out) {
    __shared__ char plds[8 * 1024];
    int b = blockIdx.y;
    int lane = threadIdx.x & 63;
    int w = threadIdx.x >> 6;
    int wn = w & 3, wc = w >> 2;
    int n_base = blockIdx.x * 64 + wn * 16;
    int c_base = wc * 128;
    int r16 = lane & 15, g = lane >> 4;

    bf16x8 qf = *(const bf16x8*)(qb + ((size_t)b * N_ + n_base + r16) * 32 + 8 * g);

    f32x4 acc[8];
#pragma unroll
    for (int j = 0; j < 8; ++j) acc[j] = (f32x4){0, 0, 0, 0};

    char* my = plds + w * 1024;
    char* wr0 = my + r16 * 64 + 8 * (g ^ (r16 & 6));
    char* wr1 = my + r16 * 64 + 8 * ((g + 4) ^ (r16 & 6));
    const char* rd = my + r16 * 64 + 8 * ((2 * g) ^ (r16 & 6));

    const unsigned short* ktb_b = ktb + (size_t)b * N_ * 32 + r16 * 32 + 8 * g;
    const unsigned short* vt_b = vtb + ((size_t)b * C_ + c_base + r16) * N_ + 8 * g;
    const float* Mb = Mcol + (size_t)b * N_ + 4 * g;

    for (int m0 = 0; m0 < N_; m0 += 32) {
        bf16x8 bv_[8];
#pragma unroll
        for (int j = 0; j < 8; ++j)
            bv_[j] = *(const bf16x8*)(vt_b + (size_t)j * 16 * N_ + m0);
        bf16x8 ka0 = *(const bf16x8*)(ktb_b + (size_t)m0 * 32);
        bf16x8 ka1 = *(const bf16x8*)(ktb_b + (size_t)(m0 + 16) * 32);
        f32x4 s0 = __builtin_amdgcn_mfma_f32_16x16x32_bf16(ka0, qf, (f32x4){0, 0, 0, 0}, 0, 0, 0);
        f32x4 s1 = __builtin_amdgcn_mfma_f32_16x16x32_bf16(ka1, qf, (f32x4){0, 0, 0, 0}, 0, 0, 0);
        float4 M0 = *(const float4*)(Mb + m0);
        float4 M1 = *(const float4*)(Mb + m0 + 16);
        unsigned p0lo = (unsigned)f2bf(fexp2(s0[0] - M0.x)) | ((unsigned)f2bf(fexp2(s0[1] - M0.y)) << 16);
        unsigned p0hi = (unsigned)f2bf(fexp2(s0[2] - M0.z)) | ((unsigned)f2bf(fexp2(s0[3] - M0.w)) << 16);
        unsigned p1lo = (unsigned)f2bf(fexp2(s1[0] - M1.x)) | ((unsigned)f2bf(fexp2(s1[1] - M1.y)) << 16);
        unsigned p1hi = (unsigned)f2bf(fexp2(s1[2] - M1.z)) | ((unsigned)f2bf(fexp2(s1[3] - M1.w)) << 16);
        *(uint2*)wr0 = make_uint2(p0lo, p0hi);
        *(uint2*)wr1 = make_uint2(p1lo, p1hi);
        __syncthreads();
        bf16x8 pa = *(const bf16x8*)rd;
#pragma unroll
        for (int j = 0; j < 8; ++j)
            acc[j] = __builtin_amdgcn_mfma_f32_16x16x32_bf16(pa, bv_[j], acc[j], 0, 0, 0);
        __syncthreads();
    }
    float gm = gamma[0];
#pragma unroll
    for (int j = 0; j < 8; ++j) {
        size_t c = c_base + j * 16 + r16;
        size_t idx = ((size_t)b * C_ + c) * N_ + n_base + 4 * g;
        float4 xv = *(const float4*)(x + idx);
        float4 o;
        o.x = gm * acc[j][0] + xv.x;
        o.y = gm * acc[j][1] + xv.y;
        o.z = gm * acc[j][2] + xv.z;
        o.w = gm * acc[j][3] + xv.w;
        *(float4*)(out + idx) = o;
    }
}

extern "C" void kernel_launch(void* const* d_in, const int* in_sizes, int n_in,
                              void* d_out, int out_size, void* d_ws, size_t ws_size,
                              hipStream_t stream) {
    const float* x = (const float*)d_in[0];
    const float* Wq = (const float*)d_in[1];
    const float* bq = (const float*)d_in[2];
    const float* Wk = (const float*)d_in[3];
    const float* bk = (const float*)d_in[4];
    const float* Wv = (const float*)d_in[5];
    const float* bv = (const float*)d_in[6];
    const float* gamma = (const float*)d_in[7];
    float* out = (float*)d_out;

    // workspace carve (bytes)
    char* ws = (char*)d_ws;
    unsigned short* qb  = (unsigned short*)(ws);                     // 4*4096*32*2 = 1 MiB
    unsigned short* ktb = (unsigned short*)(ws + (1u << 20));        // 1 MiB
    unsigned short* vtb = (unsigned short*)(ws + (2u << 20));        // 4*256*4096*2 = 8 MiB
    float* Mcol = (float*)(ws + (10u << 20));                        // 64 KiB
    float* Wcol = (float*)(ws + (10u << 20) + (1u << 16));           // 64 KiB
    float* WqkT = (float*)(ws + (10u << 20) + (2u << 16));           // 64 KiB
    float* WvT  = (float*)(ws + (10u << 20) + (3u << 16));           // 256 KiB

    k0_wprep<<<320, 256, 0, stream>>>(Wq, Wk, Wv, WqkT, WvT);
    k1_qk<<<dim3(N_ / 64, 2, B_), 64, 0, stream>>>(x, WqkT, bq, bk, qb, ktb);
    k2_stats<<<dim3(N_ / 64, B_), 256, 0, stream>>>(qb, ktb, Mcol, Wcol);
    k3_v<<<dim3(N_ / 256, C_ / 32, B_), 256, 0, stream>>>(x, WvT, bv, Wcol, vtb);
    k4_pv<<<dim3(N_ / 64, B_), 512, 0, stream>>>(x, qb, ktb, vtb, Mcol, gamma, out);
}